// Round 11
// baseline (9950.279 us; speedup 1.0000x reference)
//
#include <hip/hip_runtime.h>

// ============================================================================
// 3-layer stacked LSTM (T=2048), MI355X — round 9.
// = r6 pipeline (cached gemm loads) + r8 register-true lstm2 + 64-step chunks
//   with M=64 GEMM tiles (halved pipeline fill/drain lags) + s_setprio around
//   the LSTM critical sections.
// Roles by blockIdx (252 WGs, all co-resident):
//   [0,84)    lstm1 : 21 ch x 4 WG x 4 waves; lane = full gate row (320 f32)
//   [84,212)  lstm2 : 128 WG; wave owns 2 units, lane = 1/8 row (128 f32 regs)
//   [212,216) lstm3 : 4 WG; lane = full gate row (256 f32)
//   [216,244) gemm2 pool (28 WG): xw2 tiles 64x128, split-bf16 MFMA
//   [244,252) gemm3 pool (8 WG): xw3 tiles 64x128
// h history: packed (bf16hi|bf16lo) u32 agent stores into [2048]-row buffers
// pre-filled 0xFF; consumers poll != SENT. 64-step chunk counters gate xw.
// ============================================================================

#define T_STEPS 2048
#define SENT 0xFFFFFFFFu

using f4v   = __attribute__((ext_vector_type(4))) float;
using s8v   = __attribute__((ext_vector_type(8))) short;
using u16x8 = __attribute__((ext_vector_type(8))) unsigned short;
using u32x4 = __attribute__((ext_vector_type(4))) unsigned;

__device__ __forceinline__ unsigned short f2bf(float v) {
  unsigned u = __float_as_uint(v);
  u = (u + 0x7FFFu + ((u >> 16) & 1u)) >> 16;   // RNE
  return (unsigned short)u;
}
__device__ __forceinline__ float bf2f(unsigned short b) {
  return __uint_as_float(((unsigned)b) << 16);
}
__device__ __forceinline__ unsigned packhl(float v) {
  unsigned short hb = f2bf(v);
  unsigned short lb = f2bf(v - bf2f(hb));
  return (((unsigned)hb) << 16) | lb;
}
__device__ __forceinline__ float unpackhl(unsigned p) {
  return __uint_as_float(p & 0xFFFF0000u) + __uint_as_float(p << 16);
}
__device__ __forceinline__ float sigm(float x) { return 1.0f / (1.0f + __expf(-x)); }
__device__ __forceinline__ float tanh_f(float x) {
  float ax = fabsf(x);
  float e = __expf(-2.0f * ax);
  float t = (1.0f - e) / (1.0f + e);
  return copysignf(t, x);
}
__device__ __forceinline__ unsigned ld_agent32(const unsigned* p) {
  return __hip_atomic_load(p, __ATOMIC_RELAXED, __HIP_MEMORY_SCOPE_AGENT);
}
__device__ __forceinline__ void st_agent32(unsigned* p, unsigned v) {
  __hip_atomic_store(p, v, __ATOMIC_RELAXED, __HIP_MEMORY_SCOPE_AGENT);
}
__device__ __forceinline__ void ctr_add(unsigned* p) {
  __hip_atomic_fetch_add(p, 1u, __ATOMIC_RELAXED, __HIP_MEMORY_SCOPE_AGENT);
}
__device__ __forceinline__ void poll_ctr(const unsigned* p, unsigned tgt) {
  unsigned n = 0;
  while (ld_agent32(p) < tgt) {
    if (++n > (1u << 22)) break;               // parachute
    __builtin_amdgcn_s_sleep(4);
  }
}
// One coherent 16B load (bypasses L1/L2, reads LLC), single waitcnt.
__device__ __forceinline__ u32x4 ld16_coh(const unsigned* addr) {
  u32x4 c;
  asm volatile("global_load_dwordx4 %0, %1, off sc0 sc1\n\t"
               "s_waitcnt vmcnt(0)"
               : "=&v"(c) : "v"(addr) : "memory");
  return c;
}
#define VMCNT0() asm volatile("s_waitcnt vmcnt(0)" ::: "memory")

#define ISSUE4(r0, r1, r2, r3, ad)                                          \
  asm volatile(                                                             \
      "global_load_dwordx4 %0, %4, off sc0 sc1\n\t"                         \
      "global_load_dwordx4 %1, %4, off offset:1024 sc0 sc1\n\t"             \
      "global_load_dwordx4 %2, %4, off offset:2048 sc0 sc1\n\t"             \
      "global_load_dwordx4 %3, %4, off offset:3072 sc0 sc1"                 \
      : "=&v"(r0), "=&v"(r1), "=&v"(r2), "=&v"(r3) : "v"(ad) : "memory")
#define OK4(r0, r1, r2, r3)                                                 \
  ((r0[0] != SENT) && (r0[1] != SENT) && (r0[2] != SENT) && (r0[3] != SENT) && \
   (r1[0] != SENT) && (r1[1] != SENT) && (r1[2] != SENT) && (r1[3] != SENT) && \
   (r2[0] != SENT) && (r2[1] != SENT) && (r2[2] != SENT) && (r2[3] != SENT) && \
   (r3[0] != SENT) && (r3[1] != SENT) && (r3[2] != SENT) && (r3[3] != SENT))

#define L16(M) M(0) M(1) M(2) M(3) M(4) M(5) M(6) M(7) M(8) M(9) M(10) M(11) \
  M(12) M(13) M(14) M(15)
#define L32(M) L16(M) M(16) M(17) M(18) M(19) M(20) M(21) M(22) M(23) M(24) \
  M(25) M(26) M(27) M(28) M(29) M(30) M(31)
#define L64(M) L32(M) M(32) M(33) M(34) M(35) M(36) \
  M(37) M(38) M(39) M(40) M(41) M(42) M(43) M(44) M(45) M(46) M(47) M(48) \
  M(49) M(50) M(51) M(52) M(53) M(54) M(55) M(56) M(57) M(58) M(59) M(60) \
  M(61) M(62) M(63)

// ---------------------------------------------------------------------------
// split-bf16 GEMM tile, M-tile=64, N-tile=128. A = packed (hi|lo) u32.
// C = A*B^T + (b1+b2), agent-scope C stores. Cached (LLC-served) streams.
// ---------------------------------------------------------------------------
__device__ __forceinline__ void unpack8(u32x4 a, u32x4 b, u16x8& hi, u16x8& lo) {
#pragma unroll
  for (int j = 0; j < 4; ++j) {
    hi[j]     = (unsigned short)(a[j] >> 16);
    lo[j]     = (unsigned short)(a[j] & 0xFFFFu);
    hi[4 + j] = (unsigned short)(b[j] >> 16);
    lo[4 + j] = (unsigned short)(b[j] & 0xFFFFu);
  }
}

__device__ void gemm_tile_packed64(
    const unsigned* __restrict__ Ap, const unsigned short* __restrict__ Bh,
    const unsigned short* __restrict__ Bl, const float* __restrict__ b1,
    const float* __restrict__ b2, unsigned* __restrict__ C,
    int tm, int tn, int K, int N, char* smem)
{
  // ushort planes: Ah @0 [64][32], Al @2048, Bh @4096 [128][32], Bl @8192
  unsigned short* lds = (unsigned short*)smem;
  const size_t m0 = (size_t)tm * 64, n0 = (size_t)tn * 128;
  const int tid = threadIdx.x, lane = tid & 63, w = tid >> 6;
  const int wr = w >> 1, wc = w & 1;
  const int srow = tid >> 2, sc8 = (tid & 3) * 8;

  const unsigned* pA = Ap + m0 * K;
  const unsigned short* pBh = Bh + n0 * K;
  const unsigned short* pBl = Bl + n0 * K;

  f4v acc[2][4];
#pragma unroll
  for (int i = 0; i < 2; ++i)
#pragma unroll
    for (int j = 0; j < 4; ++j) acc[i][j] = f4v{0.f, 0.f, 0.f, 0.f};

  u32x4 a00, a01;
  u16x8 s4, s5, s6, s7;
#define LOADK(k0)                                                           \
  a00 = *(const u32x4*)(pA + (size_t)srow * K + (k0) + sc8);                \
  a01 = *(const u32x4*)(pA + (size_t)srow * K + (k0) + sc8 + 4);            \
  s4 = *(const u16x8*)(pBh + (size_t)srow * K + (k0) + sc8);                \
  s5 = *(const u16x8*)(pBh + (size_t)(srow + 64) * K + (k0) + sc8);         \
  s6 = *(const u16x8*)(pBl + (size_t)srow * K + (k0) + sc8);                \
  s7 = *(const u16x8*)(pBl + (size_t)(srow + 64) * K + (k0) + sc8);

  LOADK(0);
  const int fr = lane & 15, fko = (lane >> 4) * 8;
  for (int k0 = 0; k0 < K; k0 += 32) {
    u16x8 h0, l0;
    unpack8(a00, a01, h0, l0);
    *(u16x8*)&lds[0     + srow * 32 + sc8] = h0;
    *(u16x8*)&lds[2048  + srow * 32 + sc8] = l0;
    *(u16x8*)&lds[4096  +  srow       * 32 + sc8] = s4;
    *(u16x8*)&lds[4096  + (srow + 64) * 32 + sc8] = s5;
    *(u16x8*)&lds[8192  +  srow       * 32 + sc8] = s6;
    *(u16x8*)&lds[8192  + (srow + 64) * 32 + sc8] = s7;
    __syncthreads();
    if (k0 + 32 < K) { LOADK(k0 + 32); }
    s8v afh[2], afl[2], bfh[4], bfl[4];
#pragma unroll
    for (int i = 0; i < 2; ++i) {
      int ar = (32 * wr + 16 * i + fr) * 32 + fko;
      afh[i] = *(const s8v*)&lds[0 + ar];
      afl[i] = *(const s8v*)&lds[2048 + ar];
    }
#pragma unroll
    for (int i = 0; i < 4; ++i) {
      int br = (64 * wc + 16 * i + fr) * 32 + fko;
      bfh[i] = *(const s8v*)&lds[4096 + br];
      bfl[i] = *(const s8v*)&lds[8192 + br];
    }
#pragma unroll
    for (int mi = 0; mi < 2; ++mi)
#pragma unroll
      for (int ni = 0; ni < 4; ++ni) {
        acc[mi][ni] = __builtin_amdgcn_mfma_f32_16x16x32_bf16(afh[mi], bfh[ni], acc[mi][ni], 0, 0, 0);
        acc[mi][ni] = __builtin_amdgcn_mfma_f32_16x16x32_bf16(afh[mi], bfl[ni], acc[mi][ni], 0, 0, 0);
        acc[mi][ni] = __builtin_amdgcn_mfma_f32_16x16x32_bf16(afl[mi], bfh[ni], acc[mi][ni], 0, 0, 0);
      }
    __syncthreads();
  }
#undef LOADK
  const int er = (lane >> 4) * 4, ec = lane & 15;
#pragma unroll
  for (int ni = 0; ni < 4; ++ni) {
    size_t col = n0 + 64 * wc + 16 * ni + ec;
    float bv = b1[col] + b2[col];
#pragma unroll
    for (int mi = 0; mi < 2; ++mi) {
      size_t row = m0 + 32 * wr + 16 * mi + er;
#pragma unroll
      for (int rr = 0; rr < 4; ++rr)
        st_agent32(&C[(row + rr) * N + col], __float_as_uint(acc[mi][ni][rr] + bv));
    }
  }
}

// ---------------------------------------------------------------------------
// mega kernel
// ---------------------------------------------------------------------------
__global__ __launch_bounds__(256, 1) void mega_kernel(
    const float* __restrict__ x,
    const float* __restrict__ Wih1, const float* __restrict__ Whh1,
    const float* __restrict__ bih1, const float* __restrict__ bhh1,
    const float* __restrict__ Whh2,
    const float* __restrict__ bih2, const float* __restrict__ bhh2,
    const float* __restrict__ Whh3,
    const float* __restrict__ bih3, const float* __restrict__ bhh3,
    unsigned* __restrict__ h1r0, unsigned* __restrict__ h2r0,
    unsigned* __restrict__ h3r0, unsigned* __restrict__ cnt,
    unsigned* __restrict__ h1rows, unsigned* __restrict__ h2rows,
    unsigned* __restrict__ h3rows,
    float* __restrict__ xw2, float* __restrict__ xw3,
    const unsigned short* __restrict__ wih2h, const unsigned short* __restrict__ wih2l,
    const unsigned short* __restrict__ wih3h, const unsigned short* __restrict__ wih3l)
{
  __shared__ __align__(16) char smem[24576];
  unsigned* ready1 = cnt + 0;    // [32] tgt 336  (per-64-step chunk)
  unsigned* done2  = cnt + 32;   // [32] tgt 32   (per 64-row tm)
  unsigned* ready2 = cnt + 64;   // [32] tgt 512
  unsigned* done3  = cnt + 96;   // [32] tgt 8
  const int wg = blockIdx.x;
  const int widx = threadIdx.x >> 6, lane = threadIdx.x & 63;

  if (wg < 84) {
    // -------- lstm1: wave-autonomous; lane = full gate row ------------------
    const int c = wg / 4, sub = wg % 4;
    const int gwv = sub * 4 + widx;            // 0..15
    const int u16i = lane & 15, g = lane >> 4;
    const int grow = g * 256 + gwv * 16 + u16i;

    const f4v* wsrc = (const f4v*)(Whh1 + (size_t)grow * 256);
    const f4v* xsrc = (const f4v*)(Wih1 + (size_t)grow * 64);
#define DH(i) f4v m##i = wsrc[i];
#define DX(i) f4v n##i = xsrc[i];
    L64(DH)
    L16(DX)
#undef DH
#undef DX
    const float bias = bih1[grow] + bhh1[grow];

    float* const hb = (float*)smem + widx * 320;   // h[256] + x[64]
    float* const xq = hb + 256;

    float cst = 0.0f;
    float xpre = x[(size_t)lane * 21 + c];

    for (int t = 0; t < T_STEPS; ++t) {
      xq[lane] = xpre;
      if (t + 1 < T_STEPS) xpre = x[(size_t)(t + 1) * 1344 + lane * 21 + c];
      const unsigned* src = t ? h1rows + (size_t)(t - 1) * 5376 + c * 256
                              : h1r0 + c * 256;
      const unsigned* addr = src + 4 * lane;
      u32x4 c0;
      unsigned n = 0;
      for (;;) {
        c0 = ld16_coh(addr);
        bool ok = (c0[0] != SENT) && (c0[1] != SENT) &&
                  (c0[2] != SENT) && (c0[3] != SENT);
        if (ok || ++n > (1u << 18)) break;     // parachute
      }
      __builtin_amdgcn_s_setprio(1);
      *(f4v*)&hb[4 * lane] = f4v{unpackhl(c0[0]), unpackhl(c0[1]),
                                 unpackhl(c0[2]), unpackhl(c0[3])};
      float a0 = 0, a1 = 0, a2 = 0, a3 = 0;
#define FH(i) { f4v h4 = *(const f4v*)&hb[4 * i]; \
  a0 = fmaf(m##i[0], h4[0], a0); a1 = fmaf(m##i[1], h4[1], a1); \
  a2 = fmaf(m##i[2], h4[2], a2); a3 = fmaf(m##i[3], h4[3], a3); }
#define FX(i) { f4v x4 = *(const f4v*)&xq[4 * i]; \
  a0 = fmaf(n##i[0], x4[0], a0); a1 = fmaf(n##i[1], x4[1], a1); \
  a2 = fmaf(n##i[2], x4[2], a2); a3 = fmaf(n##i[3], x4[3], a3); }
      L64(FH)
      L16(FX)
#undef FH
#undef FX
      float z = (a0 + a1) + (a2 + a3) + bias;
      float zi = __shfl(z, u16i);
      float zf = __shfl(z, 16 + u16i);
      float zg = __shfl(z, 32 + u16i);
      float zo = __shfl(z, 48 + u16i);
      if (lane < 16) {
        float cn = sigm(zf) * cst + sigm(zi) * tanh_f(zg);
        float hn = sigm(zo) * tanh_f(cn);
        cst = cn;
        st_agent32(&h1rows[(size_t)t * 5376 + c * 256 + gwv * 16 + lane], packhl(hn));
      }
      __builtin_amdgcn_s_setprio(0);
      if ((t & 63) == 63) {
        VMCNT0();
        if (lane == 0) ctr_add(&ready1[t >> 6]);
      }
    }
  } else if (wg < 212) {
    // -------- lstm2: 128 WGs; wave owns 2 units; lane = 1/8 row (regs) ------
    const int gw = (wg - 84) * 4 + widx;       // 0..511
    const int r8 = lane >> 3, e = lane & 7;    // row-in-wave, eighth
    const int g = r8 >> 1, u = r8 & 1;
    const int grow = g * 1024 + 2 * gw + u;

    const f4v* wsrc = (const f4v*)(Whh2 + (size_t)grow * 1024 + e * 128);
#define DW(i) f4v w##i = wsrc[i];
    L32(DW)
#undef DW
    asm volatile("" : "+v"(w0), "+v"(w1), "+v"(w2), "+v"(w3),
                      "+v"(w4), "+v"(w5), "+v"(w6), "+v"(w7));
    asm volatile("" : "+v"(w8), "+v"(w9), "+v"(w10), "+v"(w11),
                      "+v"(w12), "+v"(w13), "+v"(w14), "+v"(w15));
    asm volatile("" : "+v"(w16), "+v"(w17), "+v"(w18), "+v"(w19),
                      "+v"(w20), "+v"(w21), "+v"(w22), "+v"(w23));
    asm volatile("" : "+v"(w24), "+v"(w25), "+v"(w26), "+v"(w27),
                      "+v"(w28), "+v"(w29), "+v"(w30), "+v"(w31));

    // per-wave h staging: 8 eighths x 132 f32 (skew 4 -> conflict-free)
    float* const hls = (float*)smem + widx * 1060;
    const float* const eb = hls + e * 132;
    const int sb = (lane >> 5) * 132 + 4 * (lane & 31);
    const int ug = lane & 1;

    float cst = 0.0f;
    float xwi = 0, xwf = 0, xwg = 0, xwo = 0;

    for (int t = 0; t < T_STEPS; ++t) {
      if ((t & 63) == 0) {
        poll_ctr(&done2[t >> 6], 32);
        if (lane < 2) {
          const float* xp = xw2 + (size_t)t * 4096 + 2 * gw + lane;
          xwi = xp[0]; xwf = xp[1024]; xwg = xp[2048]; xwo = xp[3072];
        }
      }
      {
        const unsigned* src = t ? h2rows + (size_t)(t - 1) * 1024 : h2r0;
        const unsigned* addr = src + 4 * lane;
        u32x4 c0, c1, c2, c3;
        unsigned n = 0;
        for (;;) {
          ISSUE4(c0, c1, c2, c3, addr);
          asm volatile("s_waitcnt vmcnt(0)"
                       : "+v"(c0), "+v"(c1), "+v"(c2), "+v"(c3) :: "memory");
          if (OK4(c0, c1, c2, c3) || ++n > (1u << 18)) break;
        }
        __builtin_amdgcn_s_setprio(1);
        *(f4v*)&hls[sb]       = f4v{unpackhl(c0[0]), unpackhl(c0[1]), unpackhl(c0[2]), unpackhl(c0[3])};
        *(f4v*)&hls[sb + 264] = f4v{unpackhl(c1[0]), unpackhl(c1[1]), unpackhl(c1[2]), unpackhl(c1[3])};
        *(f4v*)&hls[sb + 528] = f4v{unpackhl(c2[0]), unpackhl(c2[1]), unpackhl(c2[2]), unpackhl(c2[3])};
        *(f4v*)&hls[sb + 792] = f4v{unpackhl(c3[0]), unpackhl(c3[1]), unpackhl(c3[2]), unpackhl(c3[3])};
      }
      float a0 = 0, a1 = 0, a2 = 0, a3 = 0;
#define FW(i) { f4v h4 = *(const f4v*)&eb[4 * i]; \
  a0 = fmaf(w##i[0], h4[0], a0); a1 = fmaf(w##i[1], h4[1], a1); \
  a2 = fmaf(w##i[2], h4[2], a2); a3 = fmaf(w##i[3], h4[3], a3); }
      L32(FW)
#undef FW
      float z = (a0 + a1) + (a2 + a3);
      z += __shfl_xor(z, 1);
      z += __shfl_xor(z, 2);
      z += __shfl_xor(z, 4);                   // full row sums
      float zi = __shfl(z, (0 + ug) * 8);
      float zf = __shfl(z, (2 + ug) * 8);
      float zg2 = __shfl(z, (4 + ug) * 8);
      float zo = __shfl(z, (6 + ug) * 8);
      if (lane < 2) {
        float vi = zi + xwi, vf = zf + xwf, vg = zg2 + xwg, vo = zo + xwo;
        float cn = sigm(vf) * cst + sigm(vi) * tanh_f(vg);
        float hn = sigm(vo) * tanh_f(cn);
        cst = cn;
        st_agent32(&h2rows[(size_t)t * 1024 + 2 * gw + lane], packhl(hn));
      }
      __builtin_amdgcn_s_setprio(0);
      if ((t & 63) == 63) {
        VMCNT0();
        if (lane == 0) ctr_add(&ready2[t >> 6]);
      }
      if (lane < 2 && t + 1 < T_STEPS && ((t + 1) & 63) != 0) {
        const float* xp = xw2 + (size_t)(t + 1) * 4096 + 2 * gw + lane;
        xwi = xp[0]; xwf = xp[1024]; xwg = xp[2048]; xwo = xp[3072];
      }
    }
  } else if (wg < 216) {
    // -------- lstm3: wave-autonomous; lane = full gate row ------------------
    const int gw = (wg - 212) * 4 + widx;      // 0..15
    const int u16i = lane & 15, g = lane >> 4;
    const int grow = g * 256 + gw * 16 + u16i;

    const f4v* wsrc = (const f4v*)(Whh3 + (size_t)grow * 256);
#define DW(i) f4v w##i = wsrc[i];
    L64(DW)
#undef DW

    float* const hb = (float*)smem + widx * 256;
    float cst = 0.0f;
    float xwn = 0.0f;

    for (int t = 0; t < T_STEPS; ++t) {
      float xwv;
      if ((t & 63) == 0) {
        poll_ctr(&done3[t >> 6], 8);
        xwv = xw3[(size_t)t * 1024 + grow];
      } else xwv = xwn;
      const unsigned* src = t ? h3rows + (size_t)(t - 1) * 256 : h3r0;
      const unsigned* addr = src + 4 * lane;
      u32x4 c0;
      unsigned n = 0;
      for (;;) {
        c0 = ld16_coh(addr);
        bool ok = (c0[0] != SENT) && (c0[1] != SENT) &&
                  (c0[2] != SENT) && (c0[3] != SENT);
        if (ok || ++n > (1u << 18)) break;
      }
      __builtin_amdgcn_s_setprio(1);
      *(f4v*)&hb[4 * lane] = f4v{__uint_as_float(c0[0]), __uint_as_float(c0[1]),
                                 __uint_as_float(c0[2]), __uint_as_float(c0[3])};
      float a0 = 0, a1 = 0, a2 = 0, a3 = 0;
#define FW(i) { f4v h4 = *(const f4v*)&hb[4 * i]; \
  a0 = fmaf(w##i[0], h4[0], a0); a1 = fmaf(w##i[1], h4[1], a1); \
  a2 = fmaf(w##i[2], h4[2], a2); a3 = fmaf(w##i[3], h4[3], a3); }
      L64(FW)
#undef FW
      float z = (a0 + a1) + (a2 + a3) + xwv;
      float zi = __shfl(z, u16i);
      float zf = __shfl(z, 16 + u16i);
      float zg = __shfl(z, 32 + u16i);
      float zo = __shfl(z, 48 + u16i);
      if (lane < 16) {
        float cn = sigm(zf) * cst + sigm(zi) * tanh_f(zg);
        float hn = sigm(zo) * tanh_f(cn);
        cst = cn;
        st_agent32(&h3rows[(size_t)t * 256 + gw * 16 + lane], __float_as_uint(hn));
      }
      __builtin_amdgcn_s_setprio(0);
      if (t + 1 < T_STEPS && ((t + 1) & 63) != 0)
        xwn = xw3[(size_t)(t + 1) * 1024 + grow];
    }
  } else if (wg < 244) {
    // -------- gemm2 pool (28 WGs): 32 tm x 32 tn = 1024 tiles ---------------
    const int pw = wg - 216;
    for (int i = pw; i < 1024; i += 28) {
      int tm = i >> 5, tn = i & 31;
      poll_ctr(&ready1[tm], 336);
      gemm_tile_packed64(h1rows, wih2h, wih2l, bih2, bhh2,
                         (unsigned*)xw2, tm, tn, 5376, 4096, smem);
      VMCNT0();
      __syncthreads();
      if (threadIdx.x == 0) ctr_add(&done2[tm]);
      __syncthreads();
    }
  } else {
    // -------- gemm3 pool (8 WGs): 32 tm x 8 tn = 256 tiles ------------------
    const int pw = wg - 244;
    for (int i = pw; i < 256; i += 8) {
      int tm = i >> 3, tn = i & 7;
      poll_ctr(&ready2[tm], 512);
      gemm_tile_packed64(h2rows, wih3h, wih3l, bih3, bhh3,
                         (unsigned*)xw3, tm, tn, 1024, 1024, smem);
      VMCNT0();
      __syncthreads();
      if (threadIdx.x == 0) ctr_add(&done3[tm]);
      __syncthreads();
    }
  }
}

// ---------------------------------------------------------------------------
__global__ void split_kernel(const float* __restrict__ src,
                             unsigned short* __restrict__ hi,
                             unsigned short* __restrict__ lo, int n) {
  int i = blockIdx.x * 256 + threadIdx.x;
  if (i < n) {
    float v = src[i];
    unsigned short hb = f2bf(v);
    hi[i] = hb;
    lo[i] = f2bf(v - bf2f(hb));
  }
}

__global__ void fc_kernel(const float* __restrict__ h3, const float* __restrict__ Wfc,
                          const float* __restrict__ bfc, float* __restrict__ out) {
  int t = blockIdx.x, m = threadIdx.x;
  if (m < 21) {
    const float* hp = h3 + (size_t)t * 256;
    const float* wp = Wfc + m * 256;
    float a = 0.0f;
#pragma unroll 8
    for (int j = 0; j < 256; ++j) a = fmaf(wp[j], hp[j], a);
    out[t * 21 + m] = a + bfc[m];
  }
}

// ---------------------------------------------------------------------------
extern "C" void kernel_launch(void* const* d_in, const int* in_sizes, int n_in,
                              void* d_out, int out_size, void* d_ws, size_t ws_size,
                              hipStream_t stream) {
  const float* x    = (const float*)d_in[0];
  const float* Wih1 = (const float*)d_in[1];
  const float* Whh1 = (const float*)d_in[2];
  const float* bih1 = (const float*)d_in[3];
  const float* bhh1 = (const float*)d_in[4];
  const float* Wih2 = (const float*)d_in[5];
  const float* Whh2 = (const float*)d_in[6];
  const float* bih2 = (const float*)d_in[7];
  const float* bhh2 = (const float*)d_in[8];
  const float* Wih3 = (const float*)d_in[9];
  const float* Whh3 = (const float*)d_in[10];
  const float* bih3 = (const float*)d_in[11];
  const float* bhh3 = (const float*)d_in[12];
  const float* Wfc  = (const float*)d_in[13];
  const float* bfc  = (const float*)d_in[14];
  float* out = (float*)d_out;

  const size_t WS_NEEDED = 188776448;
  if (ws_size < WS_NEEDED) return;
  char* ws = (char*)d_ws;
  unsigned* h1r0 = (unsigned*)(ws + 0);
  unsigned* h2r0 = (unsigned*)(ws + 21504);
  unsigned* h3r0 = (unsigned*)(ws + 25600);
  unsigned* cnt  = (unsigned*)(ws + 26624);
  unsigned* h1rows = (unsigned*)(ws + 32768);
  unsigned* h2rows = (unsigned*)(ws + 44072960);
  unsigned* h3rows = (unsigned*)(ws + 52461568);
  float* xw2 = (float*)(ws + 54558720);
  float* xw3 = (float*)(ws + 88113152);
  unsigned short* wih2h = (unsigned short*)(ws + 96501760);
  unsigned short* wih2l = (unsigned short*)(ws + 140541952);
  unsigned short* wih3h = (unsigned short*)(ws + 184582144);
  unsigned short* wih3l = (unsigned short*)(ws + 186679296);

  hipMemsetAsync(ws, 0, 32768, stream);
  hipMemsetAsync(ws + 32768, 0xFF, 54525952, stream);

  const int nW2 = 4096 * 5376;
  split_kernel<<<(nW2 + 255) / 256, 256, 0, stream>>>(Wih2, wih2h, wih2l, nW2);
  const int nW3 = 1024 * 1024;
  split_kernel<<<(nW3 + 255) / 256, 256, 0, stream>>>(Wih3, wih3h, wih3l, nW3);

  mega_kernel<<<252, 256, 0, stream>>>(
      x, Wih1, Whh1, bih1, bhh1,
      Whh2, bih2, bhh2, Whh3, bih3, bhh3,
      h1r0, h2r0, h3r0, cnt,
      h1rows, h2rows, h3rows, xw2, xw3,
      wih2h, wih2l, wih3h, wih3l);

  fc_kernel<<<2048, 64, 0, stream>>>((const float*)h3rows, Wfc, bfc, out);
}

// Round 12
// 9030.326 us; speedup vs baseline: 1.1019x; 1.1019x over previous
//
#include <hip/hip_runtime.h>

// ============================================================================
// 3-layer stacked LSTM (T=2048), MI355X — round 10.
// = r9, minus LLC poll-storm: ONE polling wave per WG (widx0) stages h into
//   WG-shared double-buffered LDS (+1 __syncthreads/step), s_sleep(1) backoff
//   in all data polls. Poll population 852 -> 216 waves, duty cycle ~1/3.
// Roles by blockIdx (252 WGs, all co-resident):
//   [0,84)    lstm1 : 21 ch x 4 WG x 4 waves; lane = full gate row (320 f32)
//   [84,212)  lstm2 : 128 WG; wave owns 2 units, lane = 1/8 row (128 f32 regs)
//   [212,216) lstm3 : 4 WG; lane = full gate row (256 f32)
//   [216,244) gemm2 pool (28 WG): xw2 tiles 64x128, split-bf16 MFMA
//   [244,252) gemm3 pool (8 WG): xw3 tiles 64x128
// h history: packed (bf16hi|bf16lo) u32 agent stores into [2048]-row buffers
// pre-filled 0xFF; consumers poll != SENT. 64-step chunk counters gate xw.
// ============================================================================

#define T_STEPS 2048
#define SENT 0xFFFFFFFFu

using f4v   = __attribute__((ext_vector_type(4))) float;
using s8v   = __attribute__((ext_vector_type(8))) short;
using u16x8 = __attribute__((ext_vector_type(8))) unsigned short;
using u32x4 = __attribute__((ext_vector_type(4))) unsigned;

__device__ __forceinline__ unsigned short f2bf(float v) {
  unsigned u = __float_as_uint(v);
  u = (u + 0x7FFFu + ((u >> 16) & 1u)) >> 16;   // RNE
  return (unsigned short)u;
}
__device__ __forceinline__ float bf2f(unsigned short b) {
  return __uint_as_float(((unsigned)b) << 16);
}
__device__ __forceinline__ unsigned packhl(float v) {
  unsigned short hb = f2bf(v);
  unsigned short lb = f2bf(v - bf2f(hb));
  return (((unsigned)hb) << 16) | lb;
}
__device__ __forceinline__ float unpackhl(unsigned p) {
  return __uint_as_float(p & 0xFFFF0000u) + __uint_as_float(p << 16);
}
__device__ __forceinline__ float sigm(float x) { return 1.0f / (1.0f + __expf(-x)); }
__device__ __forceinline__ float tanh_f(float x) {
  float ax = fabsf(x);
  float e = __expf(-2.0f * ax);
  float t = (1.0f - e) / (1.0f + e);
  return copysignf(t, x);
}
__device__ __forceinline__ unsigned ld_agent32(const unsigned* p) {
  return __hip_atomic_load(p, __ATOMIC_RELAXED, __HIP_MEMORY_SCOPE_AGENT);
}
__device__ __forceinline__ void st_agent32(unsigned* p, unsigned v) {
  __hip_atomic_store(p, v, __ATOMIC_RELAXED, __HIP_MEMORY_SCOPE_AGENT);
}
__device__ __forceinline__ void ctr_add(unsigned* p) {
  __hip_atomic_fetch_add(p, 1u, __ATOMIC_RELAXED, __HIP_MEMORY_SCOPE_AGENT);
}
__device__ __forceinline__ void poll_ctr(const unsigned* p, unsigned tgt) {
  unsigned n = 0;
  while (ld_agent32(p) < tgt) {
    if (++n > (1u << 22)) break;               // parachute
    __builtin_amdgcn_s_sleep(4);
  }
}
// One coherent 16B load (bypasses L1/L2, reads LLC), single waitcnt.
__device__ __forceinline__ u32x4 ld16_coh(const unsigned* addr) {
  u32x4 c;
  asm volatile("global_load_dwordx4 %0, %1, off sc0 sc1\n\t"
               "s_waitcnt vmcnt(0)"
               : "=&v"(c) : "v"(addr) : "memory");
  return c;
}
#define VMCNT0() asm volatile("s_waitcnt vmcnt(0)" ::: "memory")

#define ISSUE4(r0, r1, r2, r3, ad)                                          \
  asm volatile(                                                             \
      "global_load_dwordx4 %0, %4, off sc0 sc1\n\t"                         \
      "global_load_dwordx4 %1, %4, off offset:1024 sc0 sc1\n\t"             \
      "global_load_dwordx4 %2, %4, off offset:2048 sc0 sc1\n\t"             \
      "global_load_dwordx4 %3, %4, off offset:3072 sc0 sc1"                 \
      : "=&v"(r0), "=&v"(r1), "=&v"(r2), "=&v"(r3) : "v"(ad) : "memory")
#define OK4(r0, r1, r2, r3)                                                 \
  ((r0[0] != SENT) && (r0[1] != SENT) && (r0[2] != SENT) && (r0[3] != SENT) && \
   (r1[0] != SENT) && (r1[1] != SENT) && (r1[2] != SENT) && (r1[3] != SENT) && \
   (r2[0] != SENT) && (r2[1] != SENT) && (r2[2] != SENT) && (r2[3] != SENT) && \
   (r3[0] != SENT) && (r3[1] != SENT) && (r3[2] != SENT) && (r3[3] != SENT))

#define L16(M) M(0) M(1) M(2) M(3) M(4) M(5) M(6) M(7) M(8) M(9) M(10) M(11) \
  M(12) M(13) M(14) M(15)
#define L32(M) L16(M) M(16) M(17) M(18) M(19) M(20) M(21) M(22) M(23) M(24) \
  M(25) M(26) M(27) M(28) M(29) M(30) M(31)
#define L64(M) L32(M) M(32) M(33) M(34) M(35) M(36) \
  M(37) M(38) M(39) M(40) M(41) M(42) M(43) M(44) M(45) M(46) M(47) M(48) \
  M(49) M(50) M(51) M(52) M(53) M(54) M(55) M(56) M(57) M(58) M(59) M(60) \
  M(61) M(62) M(63)

// ---------------------------------------------------------------------------
// split-bf16 GEMM tile, M-tile=64, N-tile=128. A = packed (hi|lo) u32.
// ---------------------------------------------------------------------------
__device__ __forceinline__ void unpack8(u32x4 a, u32x4 b, u16x8& hi, u16x8& lo) {
#pragma unroll
  for (int j = 0; j < 4; ++j) {
    hi[j]     = (unsigned short)(a[j] >> 16);
    lo[j]     = (unsigned short)(a[j] & 0xFFFFu);
    hi[4 + j] = (unsigned short)(b[j] >> 16);
    lo[4 + j] = (unsigned short)(b[j] & 0xFFFFu);
  }
}

__device__ void gemm_tile_packed64(
    const unsigned* __restrict__ Ap, const unsigned short* __restrict__ Bh,
    const unsigned short* __restrict__ Bl, const float* __restrict__ b1,
    const float* __restrict__ b2, unsigned* __restrict__ C,
    int tm, int tn, int K, int N, char* smem)
{
  unsigned short* lds = (unsigned short*)smem;
  const size_t m0 = (size_t)tm * 64, n0 = (size_t)tn * 128;
  const int tid = threadIdx.x, lane = tid & 63, w = tid >> 6;
  const int wr = w >> 1, wc = w & 1;
  const int srow = tid >> 2, sc8 = (tid & 3) * 8;

  const unsigned* pA = Ap + m0 * K;
  const unsigned short* pBh = Bh + n0 * K;
  const unsigned short* pBl = Bl + n0 * K;

  f4v acc[2][4];
#pragma unroll
  for (int i = 0; i < 2; ++i)
#pragma unroll
    for (int j = 0; j < 4; ++j) acc[i][j] = f4v{0.f, 0.f, 0.f, 0.f};

  u32x4 a00, a01;
  u16x8 s4, s5, s6, s7;
#define LOADK(k0)                                                           \
  a00 = *(const u32x4*)(pA + (size_t)srow * K + (k0) + sc8);                \
  a01 = *(const u32x4*)(pA + (size_t)srow * K + (k0) + sc8 + 4);            \
  s4 = *(const u16x8*)(pBh + (size_t)srow * K + (k0) + sc8);                \
  s5 = *(const u16x8*)(pBh + (size_t)(srow + 64) * K + (k0) + sc8);         \
  s6 = *(const u16x8*)(pBl + (size_t)srow * K + (k0) + sc8);                \
  s7 = *(const u16x8*)(pBl + (size_t)(srow + 64) * K + (k0) + sc8);

  LOADK(0);
  const int fr = lane & 15, fko = (lane >> 4) * 8;
  for (int k0 = 0; k0 < K; k0 += 32) {
    u16x8 h0, l0;
    unpack8(a00, a01, h0, l0);
    *(u16x8*)&lds[0     + srow * 32 + sc8] = h0;
    *(u16x8*)&lds[2048  + srow * 32 + sc8] = l0;
    *(u16x8*)&lds[4096  +  srow       * 32 + sc8] = s4;
    *(u16x8*)&lds[4096  + (srow + 64) * 32 + sc8] = s5;
    *(u16x8*)&lds[8192  +  srow       * 32 + sc8] = s6;
    *(u16x8*)&lds[8192  + (srow + 64) * 32 + sc8] = s7;
    __syncthreads();
    if (k0 + 32 < K) { LOADK(k0 + 32); }
    s8v afh[2], afl[2], bfh[4], bfl[4];
#pragma unroll
    for (int i = 0; i < 2; ++i) {
      int ar = (32 * wr + 16 * i + fr) * 32 + fko;
      afh[i] = *(const s8v*)&lds[0 + ar];
      afl[i] = *(const s8v*)&lds[2048 + ar];
    }
#pragma unroll
    for (int i = 0; i < 4; ++i) {
      int br = (64 * wc + 16 * i + fr) * 32 + fko;
      bfh[i] = *(const s8v*)&lds[4096 + br];
      bfl[i] = *(const s8v*)&lds[8192 + br];
    }
#pragma unroll
    for (int mi = 0; mi < 2; ++mi)
#pragma unroll
      for (int ni = 0; ni < 4; ++ni) {
        acc[mi][ni] = __builtin_amdgcn_mfma_f32_16x16x32_bf16(afh[mi], bfh[ni], acc[mi][ni], 0, 0, 0);
        acc[mi][ni] = __builtin_amdgcn_mfma_f32_16x16x32_bf16(afh[mi], bfl[ni], acc[mi][ni], 0, 0, 0);
        acc[mi][ni] = __builtin_amdgcn_mfma_f32_16x16x32_bf16(afl[mi], bfh[ni], acc[mi][ni], 0, 0, 0);
      }
    __syncthreads();
  }
#undef LOADK
  const int er = (lane >> 4) * 4, ec = lane & 15;
#pragma unroll
  for (int ni = 0; ni < 4; ++ni) {
    size_t col = n0 + 64 * wc + 16 * ni + ec;
    float bv = b1[col] + b2[col];
#pragma unroll
    for (int mi = 0; mi < 2; ++mi) {
      size_t row = m0 + 32 * wr + 16 * mi + er;
#pragma unroll
      for (int rr = 0; rr < 4; ++rr)
        st_agent32(&C[(row + rr) * N + col], __float_as_uint(acc[mi][ni][rr] + bv));
    }
  }
}

// ---------------------------------------------------------------------------
// mega kernel
// ---------------------------------------------------------------------------
__global__ __launch_bounds__(256, 1) void mega_kernel(
    const float* __restrict__ x,
    const float* __restrict__ Wih1, const float* __restrict__ Whh1,
    const float* __restrict__ bih1, const float* __restrict__ bhh1,
    const float* __restrict__ Whh2,
    const float* __restrict__ bih2, const float* __restrict__ bhh2,
    const float* __restrict__ Whh3,
    const float* __restrict__ bih3, const float* __restrict__ bhh3,
    unsigned* __restrict__ h1r0, unsigned* __restrict__ h2r0,
    unsigned* __restrict__ h3r0, unsigned* __restrict__ cnt,
    unsigned* __restrict__ h1rows, unsigned* __restrict__ h2rows,
    unsigned* __restrict__ h3rows,
    float* __restrict__ xw2, float* __restrict__ xw3,
    const unsigned short* __restrict__ wih2h, const unsigned short* __restrict__ wih2l,
    const unsigned short* __restrict__ wih3h, const unsigned short* __restrict__ wih3l)
{
  __shared__ __align__(16) char smem[24576];
  unsigned* ready1 = cnt + 0;    // [32] tgt 336  (per-64-step chunk)
  unsigned* done2  = cnt + 32;   // [32] tgt 32
  unsigned* ready2 = cnt + 64;   // [32] tgt 512
  unsigned* done3  = cnt + 96;   // [32] tgt 8
  const int wg = blockIdx.x;
  const int widx = threadIdx.x >> 6, lane = threadIdx.x & 63;

  if (wg < 84) {
    // -------- lstm1: widx0 polls + stages to WG-shared dbuf LDS -------------
    const int c = wg / 4, sub = wg % 4;
    const int gwv = sub * 4 + widx;            // 0..15
    const int u16i = lane & 15, g = lane >> 4;
    const int grow = g * 256 + gwv * 16 + u16i;

    const f4v* wsrc = (const f4v*)(Whh1 + (size_t)grow * 256);
    const f4v* xsrc = (const f4v*)(Wih1 + (size_t)grow * 64);
#define DH(i) f4v m##i = wsrc[i];
#define DX(i) f4v n##i = xsrc[i];
    L64(DH)
    L16(DX)
#undef DH
#undef DX
    const float bias = bih1[grow] + bhh1[grow];

    float* const hbuf = (float*)smem;          // [2][320]: h[256] + x[64]
    float cst = 0.0f;
    float xpre = (widx == 0) ? x[(size_t)lane * 21 + c] : 0.0f;

    for (int t = 0; t < T_STEPS; ++t) {
      float* const hb = hbuf + (t & 1) * 320;
      if (widx == 0) {
        hb[256 + lane] = xpre;
        if (t + 1 < T_STEPS) xpre = x[(size_t)(t + 1) * 1344 + lane * 21 + c];
        const unsigned* src = t ? h1rows + (size_t)(t - 1) * 5376 + c * 256
                                : h1r0 + c * 256;
        const unsigned* addr = src + 4 * lane;
        u32x4 c0;
        unsigned n = 0;
        for (;;) {
          c0 = ld16_coh(addr);
          bool ok = (c0[0] != SENT) && (c0[1] != SENT) &&
                    (c0[2] != SENT) && (c0[3] != SENT);
          if (ok || ++n > (1u << 18)) break;   // parachute
          __builtin_amdgcn_s_sleep(1);         // backoff: cut LLC poll load
        }
        *(f4v*)&hb[4 * lane] = f4v{unpackhl(c0[0]), unpackhl(c0[1]),
                                   unpackhl(c0[2]), unpackhl(c0[3])};
      }
      __syncthreads();
      __builtin_amdgcn_s_setprio(1);
      float a0 = 0, a1 = 0, a2 = 0, a3 = 0;
#define FH(i) { f4v h4 = *(const f4v*)&hb[4 * i]; \
  a0 = fmaf(m##i[0], h4[0], a0); a1 = fmaf(m##i[1], h4[1], a1); \
  a2 = fmaf(m##i[2], h4[2], a2); a3 = fmaf(m##i[3], h4[3], a3); }
#define FX(i) { f4v x4 = *(const f4v*)&hb[256 + 4 * i]; \
  a0 = fmaf(n##i[0], x4[0], a0); a1 = fmaf(n##i[1], x4[1], a1); \
  a2 = fmaf(n##i[2], x4[2], a2); a3 = fmaf(n##i[3], x4[3], a3); }
      L64(FH)
      L16(FX)
#undef FH
#undef FX
      float z = (a0 + a1) + (a2 + a3) + bias;
      float zi = __shfl(z, u16i);
      float zf = __shfl(z, 16 + u16i);
      float zg = __shfl(z, 32 + u16i);
      float zo = __shfl(z, 48 + u16i);
      if (lane < 16) {
        float cn = sigm(zf) * cst + sigm(zi) * tanh_f(zg);
        float hn = sigm(zo) * tanh_f(cn);
        cst = cn;
        st_agent32(&h1rows[(size_t)t * 5376 + c * 256 + gwv * 16 + lane], packhl(hn));
      }
      __builtin_amdgcn_s_setprio(0);
      if ((t & 63) == 63) {
        VMCNT0();
        if (lane == 0) ctr_add(&ready1[t >> 6]);
      }
    }
  } else if (wg < 212) {
    // -------- lstm2: widx0 polls + stages to WG-shared dbuf LDS -------------
    const int gw = (wg - 84) * 4 + widx;       // 0..511
    const int r8 = lane >> 3, e = lane & 7;    // row-in-wave, eighth
    const int g = r8 >> 1, u = r8 & 1;
    const int grow = g * 1024 + 2 * gw + u;

    const f4v* wsrc = (const f4v*)(Whh2 + (size_t)grow * 1024 + e * 128);
#define DW(i) f4v w##i = wsrc[i];
    L32(DW)
#undef DW
    asm volatile("" : "+v"(w0), "+v"(w1), "+v"(w2), "+v"(w3),
                      "+v"(w4), "+v"(w5), "+v"(w6), "+v"(w7));
    asm volatile("" : "+v"(w8), "+v"(w9), "+v"(w10), "+v"(w11),
                      "+v"(w12), "+v"(w13), "+v"(w14), "+v"(w15));
    asm volatile("" : "+v"(w16), "+v"(w17), "+v"(w18), "+v"(w19),
                      "+v"(w20), "+v"(w21), "+v"(w22), "+v"(w23));
    asm volatile("" : "+v"(w24), "+v"(w25), "+v"(w26), "+v"(w27),
                      "+v"(w28), "+v"(w29), "+v"(w30), "+v"(w31));

    // WG-shared h staging: [2][1056]; value v -> (v>>7)*132 + (v&127)
    float* const hbuf = (float*)smem;
    const int sb = (lane >> 5) * 132 + 4 * (lane & 31);
    const int ug = lane & 1;

    float cst = 0.0f;
    float xwi = 0, xwf = 0, xwg = 0, xwo = 0;

    for (int t = 0; t < T_STEPS; ++t) {
      if ((t & 63) == 0) {
        poll_ctr(&done2[t >> 6], 32);
        if (lane < 2) {
          const float* xp = xw2 + (size_t)t * 4096 + 2 * gw + lane;
          xwi = xp[0]; xwf = xp[1024]; xwg = xp[2048]; xwo = xp[3072];
        }
      }
      float* const hls = hbuf + (t & 1) * 1056;
      if (widx == 0) {
        const unsigned* src = t ? h2rows + (size_t)(t - 1) * 1024 : h2r0;
        const unsigned* addr = src + 4 * lane;
        u32x4 c0, c1, c2, c3;
        unsigned n = 0;
        for (;;) {
          ISSUE4(c0, c1, c2, c3, addr);
          asm volatile("s_waitcnt vmcnt(0)"
                       : "+v"(c0), "+v"(c1), "+v"(c2), "+v"(c3) :: "memory");
          if (OK4(c0, c1, c2, c3) || ++n > (1u << 18)) break;
          __builtin_amdgcn_s_sleep(1);         // backoff
        }
        *(f4v*)&hls[sb]       = f4v{unpackhl(c0[0]), unpackhl(c0[1]), unpackhl(c0[2]), unpackhl(c0[3])};
        *(f4v*)&hls[sb + 264] = f4v{unpackhl(c1[0]), unpackhl(c1[1]), unpackhl(c1[2]), unpackhl(c1[3])};
        *(f4v*)&hls[sb + 528] = f4v{unpackhl(c2[0]), unpackhl(c2[1]), unpackhl(c2[2]), unpackhl(c2[3])};
        *(f4v*)&hls[sb + 792] = f4v{unpackhl(c3[0]), unpackhl(c3[1]), unpackhl(c3[2]), unpackhl(c3[3])};
      }
      __syncthreads();
      __builtin_amdgcn_s_setprio(1);
      const float* const eb = hls + e * 132;
      float a0 = 0, a1 = 0, a2 = 0, a3 = 0;
#define FW(i) { f4v h4 = *(const f4v*)&eb[4 * i]; \
  a0 = fmaf(w##i[0], h4[0], a0); a1 = fmaf(w##i[1], h4[1], a1); \
  a2 = fmaf(w##i[2], h4[2], a2); a3 = fmaf(w##i[3], h4[3], a3); }
      L32(FW)
#undef FW
      float z = (a0 + a1) + (a2 + a3);
      z += __shfl_xor(z, 1);
      z += __shfl_xor(z, 2);
      z += __shfl_xor(z, 4);                   // full row sums
      float zi = __shfl(z, (0 + ug) * 8);
      float zf = __shfl(z, (2 + ug) * 8);
      float zg2 = __shfl(z, (4 + ug) * 8);
      float zo = __shfl(z, (6 + ug) * 8);
      if (lane < 2) {
        float vi = zi + xwi, vf = zf + xwf, vg = zg2 + xwg, vo = zo + xwo;
        float cn = sigm(vf) * cst + sigm(vi) * tanh_f(vg);
        float hn = sigm(vo) * tanh_f(cn);
        cst = cn;
        st_agent32(&h2rows[(size_t)t * 1024 + 2 * gw + lane], packhl(hn));
      }
      __builtin_amdgcn_s_setprio(0);
      if ((t & 63) == 63) {
        VMCNT0();
        if (lane == 0) ctr_add(&ready2[t >> 6]);
      }
      if (lane < 2 && t + 1 < T_STEPS && ((t + 1) & 63) != 0) {
        const float* xp = xw2 + (size_t)(t + 1) * 4096 + 2 * gw + lane;
        xwi = xp[0]; xwf = xp[1024]; xwg = xp[2048]; xwo = xp[3072];
      }
    }
  } else if (wg < 216) {
    // -------- lstm3: widx0 polls + stages to WG-shared dbuf LDS -------------
    const int gw = (wg - 212) * 4 + widx;      // 0..15
    const int u16i = lane & 15, g = lane >> 4;
    const int grow = g * 256 + gw * 16 + u16i;

    const f4v* wsrc = (const f4v*)(Whh3 + (size_t)grow * 256);
#define DW(i) f4v w##i = wsrc[i];
    L64(DW)
#undef DW

    float* const hbuf = (float*)smem;          // [2][256]
    float cst = 0.0f;
    float xwn = 0.0f;

    for (int t = 0; t < T_STEPS; ++t) {
      float xwv;
      if ((t & 63) == 0) {
        poll_ctr(&done3[t >> 6], 8);
        xwv = xw3[(size_t)t * 1024 + grow];
      } else xwv = xwn;
      float* const hb = hbuf + (t & 1) * 256;
      if (widx == 0) {
        const unsigned* src = t ? h3rows + (size_t)(t - 1) * 256 : h3r0;
        const unsigned* addr = src + 4 * lane;
        u32x4 c0;
        unsigned n = 0;
        for (;;) {
          c0 = ld16_coh(addr);
          bool ok = (c0[0] != SENT) && (c0[1] != SENT) &&
                    (c0[2] != SENT) && (c0[3] != SENT);
          if (ok || ++n > (1u << 18)) break;
          __builtin_amdgcn_s_sleep(1);         // backoff
        }
        *(f4v*)&hb[4 * lane] = f4v{__uint_as_float(c0[0]), __uint_as_float(c0[1]),
                                   __uint_as_float(c0[2]), __uint_as_float(c0[3])};
      }
      __syncthreads();
      __builtin_amdgcn_s_setprio(1);
      float a0 = 0, a1 = 0, a2 = 0, a3 = 0;
#define FW(i) { f4v h4 = *(const f4v*)&hb[4 * i]; \
  a0 = fmaf(w##i[0], h4[0], a0); a1 = fmaf(w##i[1], h4[1], a1); \
  a2 = fmaf(w##i[2], h4[2], a2); a3 = fmaf(w##i[3], h4[3], a3); }
      L64(FW)
#undef FW
      float z = (a0 + a1) + (a2 + a3) + xwv;
      float zi = __shfl(z, u16i);
      float zf = __shfl(z, 16 + u16i);
      float zg = __shfl(z, 32 + u16i);
      float zo = __shfl(z, 48 + u16i);
      if (lane < 16) {
        float cn = sigm(zf) * cst + sigm(zi) * tanh_f(zg);
        float hn = sigm(zo) * tanh_f(cn);
        cst = cn;
        st_agent32(&h3rows[(size_t)t * 256 + gw * 16 + lane], __float_as_uint(hn));
      }
      __builtin_amdgcn_s_setprio(0);
      if (t + 1 < T_STEPS && ((t + 1) & 63) != 0)
        xwn = xw3[(size_t)(t + 1) * 1024 + grow];
    }
  } else if (wg < 244) {
    // -------- gemm2 pool (28 WGs): 32 tm x 32 tn = 1024 tiles ---------------
    const int pw = wg - 216;
    for (int i = pw; i < 1024; i += 28) {
      int tm = i >> 5, tn = i & 31;
      poll_ctr(&ready1[tm], 336);
      gemm_tile_packed64(h1rows, wih2h, wih2l, bih2, bhh2,
                         (unsigned*)xw2, tm, tn, 5376, 4096, smem);
      VMCNT0();
      __syncthreads();
      if (threadIdx.x == 0) ctr_add(&done2[tm]);
      __syncthreads();
    }
  } else {
    // -------- gemm3 pool (8 WGs): 32 tm x 8 tn = 256 tiles ------------------
    const int pw = wg - 244;
    for (int i = pw; i < 256; i += 8) {
      int tm = i >> 3, tn = i & 7;
      poll_ctr(&ready2[tm], 512);
      gemm_tile_packed64(h2rows, wih3h, wih3l, bih3, bhh3,
                         (unsigned*)xw3, tm, tn, 1024, 1024, smem);
      VMCNT0();
      __syncthreads();
      if (threadIdx.x == 0) ctr_add(&done3[tm]);
      __syncthreads();
    }
  }
}

// ---------------------------------------------------------------------------
__global__ void split_kernel(const float* __restrict__ src,
                             unsigned short* __restrict__ hi,
                             unsigned short* __restrict__ lo, int n) {
  int i = blockIdx.x * 256 + threadIdx.x;
  if (i < n) {
    float v = src[i];
    unsigned short hb = f2bf(v);
    hi[i] = hb;
    lo[i] = f2bf(v - bf2f(hb));
  }
}

__global__ void fc_kernel(const float* __restrict__ h3, const float* __restrict__ Wfc,
                          const float* __restrict__ bfc, float* __restrict__ out) {
  int t = blockIdx.x, m = threadIdx.x;
  if (m < 21) {
    const float* hp = h3 + (size_t)t * 256;
    const float* wp = Wfc + m * 256;
    float a = 0.0f;
#pragma unroll 8
    for (int j = 0; j < 256; ++j) a = fmaf(wp[j], hp[j], a);
    out[t * 21 + m] = a + bfc[m];
  }
}

// ---------------------------------------------------------------------------
extern "C" void kernel_launch(void* const* d_in, const int* in_sizes, int n_in,
                              void* d_out, int out_size, void* d_ws, size_t ws_size,
                              hipStream_t stream) {
  const float* x    = (const float*)d_in[0];
  const float* Wih1 = (const float*)d_in[1];
  const float* Whh1 = (const float*)d_in[2];
  const float* bih1 = (const float*)d_in[3];
  const float* bhh1 = (const float*)d_in[4];
  const float* Wih2 = (const float*)d_in[5];
  const float* Whh2 = (const float*)d_in[6];
  const float* bih2 = (const float*)d_in[7];
  const float* bhh2 = (const float*)d_in[8];
  const float* Wih3 = (const float*)d_in[9];
  const float* Whh3 = (const float*)d_in[10];
  const float* bih3 = (const float*)d_in[11];
  const float* bhh3 = (const float*)d_in[12];
  const float* Wfc  = (const float*)d_in[13];
  const float* bfc  = (const float*)d_in[14];
  float* out = (float*)d_out;

  const size_t WS_NEEDED = 188776448;
  if (ws_size < WS_NEEDED) return;
  char* ws = (char*)d_ws;
  unsigned* h1r0 = (unsigned*)(ws + 0);
  unsigned* h2r0 = (unsigned*)(ws + 21504);
  unsigned* h3r0 = (unsigned*)(ws + 25600);
  unsigned* cnt  = (unsigned*)(ws + 26624);
  unsigned* h1rows = (unsigned*)(ws + 32768);
  unsigned* h2rows = (unsigned*)(ws + 44072960);
  unsigned* h3rows = (unsigned*)(ws + 52461568);
  float* xw2 = (float*)(ws + 54558720);
  float* xw3 = (float*)(ws + 88113152);
  unsigned short* wih2h = (unsigned short*)(ws + 96501760);
  unsigned short* wih2l = (unsigned short*)(ws + 140541952);
  unsigned short* wih3h = (unsigned short*)(ws + 184582144);
  unsigned short* wih3l = (unsigned short*)(ws + 186679296);

  hipMemsetAsync(ws, 0, 32768, stream);
  hipMemsetAsync(ws + 32768, 0xFF, 54525952, stream);

  const int nW2 = 4096 * 5376;
  split_kernel<<<(nW2 + 255) / 256, 256, 0, stream>>>(Wih2, wih2h, wih2l, nW2);
  const int nW3 = 1024 * 1024;
  split_kernel<<<(nW3 + 255) / 256, 256, 0, stream>>>(Wih3, wih3h, wih3l, nW3);

  mega_kernel<<<252, 256, 0, stream>>>(
      x, Wih1, Whh1, bih1, bhh1,
      Whh2, bih2, bhh2, Whh3, bih3, bhh3,
      h1r0, h2r0, h3r0, cnt,
      h1rows, h2rows, h3rows, xw2, xw3,
      wih2h, wih2l, wih3h, wih3l);

  fc_kernel<<<2048, 64, 0, stream>>>((const float*)h3rows, Wfc, bfc, out);
}